// Round 3
// baseline (92.759 us; speedup 1.0000x reference)
//
#include <hip/hip_runtime.h>
#include <hip/hip_bf16.h>

typedef unsigned short u16;
typedef __attribute__((ext_vector_type(8))) short short8;    // 8 bf16 (4 VGPR) MFMA A/B frag
typedef __attribute__((ext_vector_type(4))) float f32x4;     // MFMA C/D frag
typedef __attribute__((ext_vector_type(8))) unsigned short u16x8;

#define MDIM 4096
#define NDIM 1024
#define KDIM 2048
#define BM 256       // rows per block
#define BNS 64       // spatial cols per block (x4 gates)
#define BK 64
#define NT (KDIM / BK)   // 32 K-tiles

#define G_I 0
#define G_F 1
#define G_C 2
#define G_O 3

// fp32 -> bf16 round-to-nearest-even
static __device__ __forceinline__ u16 f2b(float f) {
    unsigned u = __builtin_bit_cast(unsigned, f);
    unsigned r = u + 0x7fffu + ((u >> 16) & 1u);
    return (u16)(r >> 16);
}

static __device__ __forceinline__ float sigm(float x) {
    return 1.0f / (1.0f + __expf(-x));
}

// async global->LDS 16B copy. LDS dest wave-uniform; HW adds lane*16.
static __device__ __forceinline__ void gload16(const void* g, void* l) {
    __builtin_amdgcn_global_load_lds(
        (__attribute__((address_space(1))) void*)g,
        (__attribute__((address_space(3))) void*)l, 16, 0, 0);
}

// inline-asm LDS read: opaque to compiler aliasing -> no auto vmcnt/lgkm waits.
// Pair every cluster of these with s_waitcnt lgkmcnt(0) + sched_barrier(0).
template <int IMM>
static __device__ __forceinline__ short8 ds_read_imm(unsigned addr) {
    short8 r;
    asm volatile("ds_read_b128 %0, %1 offset:%2"
                 : "=&v"(r) : "v"(addr), "i"(IMM));
    return r;
}

// ---------------------------------------------------------------------------
// Pack x,h -> bf16 xh workspace, tiled [mblk 16][kt 32][256][64] with XOR slot
// swizzle pre-applied: element (row,k) at row*64 + (((k>>3)^row)&7)*8 + (k&7)
// ---------------------------------------------------------------------------
__global__ void conv_xh_kernel(const float* __restrict__ x,
                               const float* __restrict__ h,
                               u16* __restrict__ xh_ws) {
    const int kblk = blockIdx.x;  // 0..31
    const int mblk = blockIdx.y;  // 0..15
    u16* dst = xh_ws + (size_t)(mblk * 32 + kblk) * (BM * BK);
    const float* src0;
    int kofs;
    if (kblk < 16) { src0 = x; kofs = kblk * 64; }
    else           { src0 = h; kofs = kblk * 64 - 1024; }
    for (int i = threadIdx.x; i < BM * 8; i += 256) {
        int mr = i >> 3, s = i & 7;
        const float* p = src0 + (size_t)(mblk * BM + mr) * 1024 + kofs + s * 8;
        float4 a = reinterpret_cast<const float4*>(p)[0];
        float4 b = reinterpret_cast<const float4*>(p)[1];
        u16x8 o;
        o[0] = f2b(a.x); o[1] = f2b(a.y); o[2] = f2b(a.z); o[3] = f2b(a.w);
        o[4] = f2b(b.x); o[5] = f2b(b.y); o[6] = f2b(b.z); o[7] = f2b(b.w);
        *reinterpret_cast<u16x8*>(dst + mr * 64 + ((s ^ (mr & 7)) << 3)) = o;
    }
}

// ---------------------------------------------------------------------------
// Transpose-convert W_g [K][N] fp32 -> bf16 [g][nblk 16][kt 32][64 n][64 k],
// same XOR slot swizzle on the k axis within each 64-row.
// ---------------------------------------------------------------------------
__global__ void conv_w_kernel(const float* __restrict__ Wi,
                              const float* __restrict__ Wf,
                              const float* __restrict__ Wc,
                              const float* __restrict__ Wo,
                              u16* __restrict__ w_ws) {
    const int kblk = blockIdx.x;  // 0..31
    const int nblk = blockIdx.y;  // 0..15
    const int g    = blockIdx.z;  // 0..3
    const float* W = (g == 0) ? Wi : (g == 1) ? Wf : (g == 2) ? Wc : Wo;
    u16* dst = w_ws + (size_t)((g * 16 + nblk) * 32 + kblk) * (BNS * BK);
    const int nr = threadIdx.x & 63;
    const int s0 = threadIdx.x >> 6;   // 0..3
    const int n  = nblk * 64 + nr;
    for (int s = s0; s < 8; s += 4) {
        const float* p = W + (size_t)(kblk * 64 + s * 8) * 1024 + n;
        u16x8 o;
#pragma unroll
        for (int j = 0; j < 8; ++j) o[j] = f2b(p[(size_t)j * 1024]);
        *reinterpret_cast<u16x8*>(dst + nr * 64 + ((s ^ (nr & 7)) << 3)) = o;
    }
}

// ---------------------------------------------------------------------------
// Fused 4-gate GEMM + LSTM epilogue. 8 waves (4M x 2N), tile 256m x 64n x 4g
// (= 256x256 effective). Per K-tile: 4 phases (one gate each), 16 MFMA/phase.
// All hot-loop LDS reads are inline-asm ds_read_b128 (no compiler-inserted
// waits); staging 1 K-tile ahead via global_load_lds; counted vmcnt only.
// ---------------------------------------------------------------------------
__global__ __launch_bounds__(512, 2) void lstm_gemm_kernel(
    const u16* __restrict__ xh_ws, const u16* __restrict__ w_ws,
    const float* __restrict__ c_in,
    const float* __restrict__ b_i, const float* __restrict__ b_f,
    const float* __restrict__ b_c, const float* __restrict__ b_o,
    float* __restrict__ h_out, float* __restrict__ c_out) {
    // per buffer: A 256x64 (16384 u16) + B 4x64x64 (16384 u16); x2 = 128 KiB
    __shared__ u16 lds[2 * 32768];

    const int nblk = blockIdx.x;   // 0..15
    const int mblk = blockIdx.y;   // 0..15
    const int t    = threadIdx.x;
    const int lane = t & 63;
    const int w    = t >> 6;       // 0..7
    const int wq   = w >> 1;       // m-quadrant 0..3 (64 rows each)
    const int wn   = w & 1;        // n-half 0..1 (32 cols each)
    const int l15  = lane & 15;
    const int l4   = lane >> 4;

    const size_t bstr = (size_t)NT * 4096;   // w_ws: per-(g,nblk) run of K-tiles
    // hoisted staging base pointers (only +kt*const, +const remain per stage)
    const u16* aSrc = xh_ws + (size_t)mblk * (NT * 16384) + (w * 2) * 512 + lane * 8;
    const u16* bSrc = w_ws + (size_t)nblk * bstr + w * 512 + lane * 8;
    u16* aDst = lds + (w * 2) * 512;           // + c*32768 + half*8192 (+512)
    u16* bDst = lds + 16384 + w * 512;         // + c*32768 + pb*8192 (+4096)

    // LDS read address registers (BYTE addresses) for asm ds_read.
    // swizzle slot: row&7 == l15&7 for every frag row -> slot = ((kc^l15)&7)
    const unsigned lbase = (unsigned)(uintptr_t)&lds[0];
    unsigned slot[2];
    slot[0] = (unsigned)((((0 * 4 + l4) ^ l15) & 7) * 16);
    slot[1] = (unsigned)((((1 * 4 + l4) ^ l15) & 7) * 16);
    const unsigned aCom = lbase + wq * 8192 + l15 * 128;
    const unsigned bCom = lbase + 32768 + wn * 4096 + l15 * 128;
    unsigned aReg[2][2], bReg[2][2];           // [buf c][ks], literal-indexed
#pragma unroll
    for (int c = 0; c < 2; ++c)
#pragma unroll
        for (int ks = 0; ks < 2; ++ks) {
            aReg[c][ks] = aCom + c * 65536 + slot[ks];
            bReg[c][ks] = bCom + c * 65536 + slot[ks];
        }

    f32x4 acc[4][4][2] = {};   // [gate][mf][nf]
    short8 afr[4][2];          // A frags, read once per K-tile, reused 4 gates

// ---- asm read clusters (c, ks, G are literals) ----
#define RD_A(c, ks)                                                            \
    { afr[0][ks] = ds_read_imm<0>(aReg[c][ks]);                                \
      afr[1][ks] = ds_read_imm<2048>(aReg[c][ks]);                             \
      afr[2][ks] = ds_read_imm<4096>(aReg[c][ks]);                             \
      afr[3][ks] = ds_read_imm<6144>(aReg[c][ks]); }

#define RD_B(G, c)                                                             \
    { bfr[0][0] = ds_read_imm<(G)*8192 + 0>(bReg[c][0]);                       \
      bfr[1][0] = ds_read_imm<(G)*8192 + 2048>(bReg[c][0]);                    \
      bfr[0][1] = ds_read_imm<(G)*8192 + 0>(bReg[c][1]);                       \
      bfr[1][1] = ds_read_imm<(G)*8192 + 2048>(bReg[c][1]); }

// ---- staging: 2 x global_load_lds (16B) per chunk per thread ----
#define STAGE_A(c, kt, half)                                                   \
    { const u16* s_ = aSrc + (kt) * 16384 + (half) * 8192;                     \
      u16* d_ = aDst + (c) * 32768 + (half) * 8192;                            \
      gload16(s_, d_); gload16(s_ + 512, d_ + 512); }

#define STAGE_B(c, kt, pb)                                                     \
    { const u16* s_ = bSrc + (size_t)(pb) * 2 * 16 * bstr + (kt) * 4096;       \
      u16* d_ = bDst + (c) * 32768 + (pb) * 8192;                              \
      gload16(s_, d_); gload16(s_ + 16 * bstr, d_ + 4096); }

#define VMW(N) asm volatile("s_waitcnt vmcnt(" #N ")" ::: "memory")

#define MFMA16(G)                                                              \
    _Pragma("unroll") for (int ks = 0; ks < 2; ++ks)                           \
    _Pragma("unroll") for (int mf = 0; mf < 4; ++mf)                           \
    _Pragma("unroll") for (int nf = 0; nf < 2; ++nf)                           \
        acc[G][mf][nf] = __builtin_amdgcn_mfma_f32_16x16x32_bf16(              \
            afr[mf][ks], bfr[nf][ks], acc[G][mf][nf], 0, 0, 0);

#define PH(G, c, STAGE_STMT, TAILW)                                            \
    { short8 bfr[2][2];                                                        \
      RD_B(G, c);                                                              \
      STAGE_STMT;                                                              \
      __builtin_amdgcn_s_barrier();                                            \
      asm volatile("s_waitcnt lgkmcnt(0)" ::: "memory");                       \
      __builtin_amdgcn_sched_barrier(0);                                       \
      __builtin_amdgcn_s_setprio(1);                                           \
      MFMA16(G);                                                               \
      __builtin_amdgcn_s_setprio(0);                                           \
      __builtin_amdgcn_sched_barrier(0);                                       \
      TAILW;                                                                   \
      __builtin_amdgcn_s_barrier(); }

// per K-tile: phases stage next tile's chunks {A0,A1,B01,B23}; waits:
//   ph1 tail vmcnt(4) drains current tile's B23 (2-phase slack),
//   ph3 tail vmcnt(2) drains next tile's A0,A1,B01 (3-phase slack).
#define TILE(c, kt, st)                                                        \
    RD_A(c, 0); RD_A(c, 1);                                                    \
    PH(0, c, if (st) STAGE_A((c) ^ 1, (kt) + 1, 0), );                         \
    PH(1, c, if (st) STAGE_A((c) ^ 1, (kt) + 1, 1),                            \
       if (st) { VMW(4); } else { VMW(0); });                                  \
    PH(2, c, if (st) STAGE_B((c) ^ 1, (kt) + 1, 0), );                         \
    PH(3, c, if (st) STAGE_B((c) ^ 1, (kt) + 1, 1), if (st) VMW(2));

    // ---- prologue: stage tile 0; A0,A1,B01 landed, B23 left in flight ----
    STAGE_A(0, 0, 0);
    STAGE_A(0, 0, 1);
    STAGE_B(0, 0, 0);
    STAGE_B(0, 0, 1);
    VMW(2);
    __builtin_amdgcn_s_barrier();

#pragma unroll 1
    for (int ut = 0; ut < 16; ++ut) {
        const int kt0 = ut * 2;
        TILE(0, kt0, 1)
        TILE(1, kt0 + 1, (ut < 15))
    }

    // ---- fused LSTM epilogue (all 4 gates wave-local) ----
    const int mBase = mblk * BM + wq * 64;
    const int nBase = nblk * BNS + wn * 32;
#pragma unroll
    for (int nf = 0; nf < 2; ++nf) {
        int n = nBase + nf * 16 + l15;
        float vbi = b_i[n], vbf = b_f[n], vbc = b_c[n], vbo = b_o[n];
#pragma unroll
        for (int mf = 0; mf < 4; ++mf) {
#pragma unroll
            for (int r = 0; r < 4; ++r) {
                int m = mBase + mf * 16 + l4 * 4 + r;
                size_t idx = (size_t)m * NDIM + n;
                float gi = sigm(acc[G_I][mf][nf][r] + vbi);
                float gf = sigm(acc[G_F][mf][nf][r] + vbf);
                float gc = tanhf(acc[G_C][mf][nf][r] + vbc);
                float go = sigm(acc[G_O][mf][nf][r] + vbo);
                float ct = gf * c_in[idx] + gi * gc;
                h_out[idx] = go * tanhf(ct);
                c_out[idx] = ct;
            }
        }
    }
#undef RD_A
#undef RD_B
#undef STAGE_A
#undef STAGE_B
#undef VMW
#undef MFMA16
#undef PH
#undef TILE
}

extern "C" void kernel_launch(void* const* d_in, const int* in_sizes, int n_in,
                              void* d_out, int out_size, void* d_ws, size_t ws_size,
                              hipStream_t stream) {
    const float* x   = (const float*)d_in[0];
    const float* h   = (const float*)d_in[1];
    const float* c   = (const float*)d_in[2];
    const float* Wi  = (const float*)d_in[3];
    const float* Wf  = (const float*)d_in[4];
    const float* Wc  = (const float*)d_in[5];
    const float* Wo  = (const float*)d_in[6];
    const float* bi  = (const float*)d_in[7];
    const float* bf_ = (const float*)d_in[8];
    const float* bc  = (const float*)d_in[9];
    const float* bo  = (const float*)d_in[10];

    float* hout = (float*)d_out;
    float* cout = hout + (size_t)MDIM * NDIM;

    u16* xh_ws = (u16*)d_ws;                       // bf16 xh, 16.78 MB
    u16* w_ws  = xh_ws + (size_t)MDIM * KDIM;      // bf16 W^T, 16.78 MB

    conv_xh_kernel<<<dim3(32, 16), 256, 0, stream>>>(x, h, xh_ws);
    conv_w_kernel<<<dim3(32, 16, 4), 256, 0, stream>>>(Wi, Wf, Wc, Wo, w_ws);
    lstm_gemm_kernel<<<dim3(16, 16), 512, 0, stream>>>(
        xh_ws, w_ws, c, bi, bf_, bc, bo, hout, cout);
}